// Round 5
// baseline (7516.987 us; speedup 1.0000x reference)
//
#include <hip/hip_runtime.h>
#include <hip/hip_bf16.h>

// 2-layer LSTM (T=512,B=128,IN=544,H=512) + actor/critic heads on MI355X.
// R5: R2's proven compute structure + new sync. Diagnosis: R2's 13us/step was
// flag-OBSERVATION latency -- relaxed agent atomic loads can hit a stale
// locally-cached (per-XCD L2) clean line; progress only on eviction (~L2
// turnover ~10us). Fix:
//  (a) polls are atomic RMWs (fetch_add 0) -> executed at the IF$ coherence
//      point, cannot read stale L2; per-(layer,bg,slot) counters, 32
//      producers each fetch_add(1), consumer polls ==32 (tid0 + barrier).
//  (b) h0 ring (address reuse every 16 steps) -> full 513-slot h0 history:
//      every h address is write-once-then-read (no stale-hit hazard, no
//      back-pressure spin). ws = 32KB counters + 2x67.2MB hist = 134.5MB
//      (ws_size >= 338MB established by R3/R4).
// Blocks 0..127 layer0, 128..255 layer1; per block: batch tile 32 (bg),
// hidden tile 16 (jg); weights bf16 in registers; K split over 4 waves,
// LDS reduction; h passed via agent-scope 8B atomic stores (writethrough).

namespace {
constexpr int T = 512, B = 128, H = 512, NA = 18;
constexpr int BH = B * H;                 // 65536
constexpr int OUT_COLS = NA + 1;          // 19
constexpr int OUT_HT = T * B * OUT_COLS;  // 1245184
constexpr int OUT_CT = OUT_HT + 2 * BH;   // 1376256
}

using f32x4 = __attribute__((ext_vector_type(4))) float;
using s16x8 = __attribute__((ext_vector_type(8))) short;

__device__ __forceinline__ unsigned short f2bu(float f) {
  union { __hip_bfloat16 h; unsigned short u; } cv;
  cv.h = __float2bfloat16(f);
  return cv.u;
}
__device__ __forceinline__ float sigm(float x) { return 1.0f / (1.0f + __expf(-x)); }
__device__ __forceinline__ float tanh_f(float x) { return 1.0f - 2.0f / (1.0f + __expf(2.0f * x)); }

// RMW-based poll: executed at the coherence point, immune to stale L2 hits.
__device__ __forceinline__ void poll32(unsigned int* p) {
  for (;;) {
    unsigned int v = __hip_atomic_fetch_add(p, 0u, __ATOMIC_RELAXED, __HIP_MEMORY_SCOPE_AGENT);
    if (v >= 32u) return;
    __builtin_amdgcn_s_sleep(4);
  }
}

__device__ __forceinline__ s16x8 ld_frag_agent(const unsigned short* p) {
  const unsigned long long* q = (const unsigned long long*)p;
  unsigned long long a0 = __hip_atomic_load(q, __ATOMIC_RELAXED, __HIP_MEMORY_SCOPE_AGENT);
  unsigned long long a1 = __hip_atomic_load(q + 1, __ATOMIC_RELAXED, __HIP_MEMORY_SCOPE_AGENT);
  union { unsigned long long u[2]; s16x8 v; } r;
  r.u[0] = a0; r.u[1] = a1;
  return r.v;
}

__device__ __forceinline__ s16x8 cvt8(const float* p) {
  const f32x4* q = (const f32x4*)p;
  f32x4 a = q[0], b = q[1];
  union { s16x8 v; unsigned short u[8]; } t;
#pragma unroll
  for (int j = 0; j < 4; j++) { t.u[j] = f2bu(a[j]); t.u[4 + j] = f2bu(b[j]); }
  return t.v;
}

// slot s of h-history holds h after step s-1 (slot 0 = initial h).
// cnt[(layer*4+bg)*1024 + s] counts blocks that published slot s (target 32).
template <int LAYER>
__device__ void lstm_layer(const float* __restrict__ x, const int* __restrict__ done,
                           const float* __restrict__ h0in, const float* __restrict__ c0in,
                           const float* __restrict__ Wih, const float* __restrict__ Whh,
                           const float* __restrict__ bih, const float* __restrict__ bhh,
                           float* __restrict__ out, unsigned short* __restrict__ h0h,
                           unsigned short* __restrict__ h1h, unsigned int* cnt,
                           int bg, int jg, float* red, unsigned short (*hrep)[16][20]) {
  constexpr int NKCMAX = (LAYER == 0) ? 9 : 8;
  const int tid = threadIdx.x;
  const int w = tid >> 6;
  const int lane = tid & 63;
  const int lo = lane & 15;
  const int quad = lane >> 4;
  const int bbase = bg * 32, jbase = jg * 16;
  const bool rec = (w >= 2);  // waves 2,3: recurrent operand

  int kbeg, nkc;
  if (LAYER == 0) { kbeg = (w == 0) ? 0 : (1 + w * 8); nkc = (w == 0) ? 9 : 8; }  // x: 0..16, h: 17..32
  else            { kbeg = w * 8; nkc = 8; }                                       // in: 0..15, h: 16..31

  // ---- weight B-fragments in registers ----
  s16x8 Bf[4][NKCMAX];
#pragma unroll
  for (int kci = 0; kci < NKCMAX; kci++) {
    if (kci < nkc) {
      int kg = (kbeg + kci) * 32 + quad * 8;
#pragma unroll
      for (int nt = 0; nt < 4; nt++) {
        int row = nt * 512 + jbase + lo;
        const float* src;
        if (LAYER == 0) src = (kg < 544) ? (Wih + (size_t)row * 544 + kg) : (Whh + (size_t)row * 512 + (kg - 544));
        else            src = (kg < 512) ? (Wih + (size_t)row * 512 + kg) : (Whh + (size_t)row * 512 + (kg - 512));
        Bf[nt][kci] = cvt8(src);
      }
    }
  }

  float bias[4];
#pragma unroll
  for (int nt = 0; nt < 4; nt++) {
    int row = nt * 512 + jbase + lo;
    bias[nt] = bih[row] + bhh[row];
  }

  const int mt = w & 1;
  const int bE0 = bbase + mt * 16 + quad * 4;
  const int jE = jbase + lo;
  float cst[4] = {0.f, 0.f, 0.f, 0.f};

  unsigned short* myh = (LAYER == 0) ? h0h : h1h;
  if (w < 2) {
#pragma unroll
    for (int r = 0; r < 4; r++) cst[r] = c0in[LAYER * BH + (bE0 + r) * 512 + jE];
    // initial h publication into slot 0: lane -> 8B chunk
    int bI = bbase + mt * 16 + (lane >> 2);
    int jI = jbase + (lane & 3) * 4;
    const float* hp = h0in + LAYER * BH + bI * 512 + jI;
    union { unsigned long long u; unsigned short s[4]; } pk;
#pragma unroll
    for (int j = 0; j < 4; j++) pk.s[j] = f2bu(hp[j]);
    __hip_atomic_store((unsigned long long*)(myh + bI * 512 + jI), pk.u,
                       __ATOMIC_RELAXED, __HIP_MEMORY_SCOPE_AGENT);
  }
  __syncthreads();  // drains each wave's stores (vmcnt) before publish

  unsigned int* c0a = cnt + (0 * 4 + bg) * 1024;
  unsigned int* c1a = cnt + (1 * 4 + bg) * 1024;
  unsigned int* cmy = (LAYER == 0) ? c0a : c1a;
  if (tid == 0) {
    __builtin_amdgcn_s_waitcnt(0);
    __hip_atomic_fetch_add(cmy + 0, 1u, __ATOMIC_RELAXED, __HIP_MEMORY_SCOPE_AGENT);
  }

  for (int t = 0; t < T; t++) {
    if (tid == 0) {
      if (LAYER == 0) {
        poll32(c0a + t);        // all peers published h0 slot t (h0[t-1])
      } else {
        poll32(c1a + t);        // peers' h1 slot t
        poll32(c0a + t + 1);    // layer0's h0 slot t+1 (h0[t])
      }
    }
    __syncthreads();

    const unsigned short* prec[2];
    const unsigned short* pin1[2];
    const float* pxf[2];
    bool dA[2];
#pragma unroll
    for (int m2 = 0; m2 < 2; m2++) {
      int b = bbase + m2 * 16 + lo;
      dA[m2] = rec ? (done[t * B + b] != 0) : false;
      if (LAYER == 0) {
        pxf[m2] = x + (size_t)(t * B + b) * 544 + quad * 8;
        prec[m2] = h0h + (size_t)t * BH + b * 512 + quad * 8;        // h0[t-1]
      } else {
        pin1[m2] = h0h + (size_t)(t + 1) * BH + b * 512 + quad * 8;  // h0[t]
        prec[m2] = h1h + (size_t)t * BH + b * 512 + quad * 8;        // h1[t-1]
      }
    }
    const int koff = rec ? (kbeg - (LAYER == 0 ? 17 : 16)) * 32 : kbeg * 32;

    f32x4 acc[2][4];
#pragma unroll
    for (int m2 = 0; m2 < 2; m2++)
#pragma unroll
      for (int nt = 0; nt < 4; nt++) acc[m2][nt] = (f32x4){0.f, 0.f, 0.f, 0.f};

#pragma unroll
    for (int kci = 0; kci < NKCMAX; kci++) {
      if (kci < nkc) {
        int ko = koff + kci * 32;
#pragma unroll
        for (int m2 = 0; m2 < 2; m2++) {
          s16x8 a;
          if (rec) {
            a = ld_frag_agent(prec[m2] + ko);
            if (dA[m2]) a = s16x8{};
          } else if (LAYER == 0) {
            a = cvt8(pxf[m2] + ko);
          } else {
            a = ld_frag_agent(pin1[m2] + ko);
          }
#pragma unroll
          for (int nt = 0; nt < 4; nt++)
            acc[m2][nt] = __builtin_amdgcn_mfma_f32_16x16x32_bf16(a, Bf[nt][kci], acc[m2][nt], 0, 0, 0);
        }
      }
    }

    // cross-wave K reduction through LDS
#pragma unroll
    for (int m2 = 0; m2 < 2; m2++)
#pragma unroll
      for (int nt = 0; nt < 4; nt++)
#pragma unroll
        for (int r = 0; r < 4; r++)
          red[(((w * 2 + m2) * 16) + nt * 4 + r) * 64 + lane] = acc[m2][nt][r];
    __syncthreads();

    if (w < 2) {
      float g[4][4];
#pragma unroll
      for (int nt = 0; nt < 4; nt++)
#pragma unroll
        for (int r = 0; r < 4; r++) {
          int f = nt * 4 + r;
          g[nt][r] = red[((0 * 2 + mt) * 16 + f) * 64 + lane] + red[((1 * 2 + mt) * 16 + f) * 64 + lane] +
                     red[((2 * 2 + mt) * 16 + f) * 64 + lane] + red[((3 * 2 + mt) * 16 + f) * 64 + lane];
        }
      float hnv[4], cnv[4];
#pragma unroll
      for (int r = 0; r < 4; r++) {
        int b = bE0 + r;
        float iv = g[0][r] + bias[0];
        float fv = g[1][r] + bias[1];
        float gv = g[2][r] + bias[2];
        float ov = g[3][r] + bias[3];
        float cp = (done[t * B + b] != 0) ? 0.0f : cst[r];
        float cn = sigm(fv) * cp + sigm(iv) * tanh_f(gv);
        float hn = sigm(ov) * tanh_f(cn);
        cst[r] = cn; hnv[r] = hn; cnv[r] = cn;
        hrep[mt][quad * 4 + r][lo] = f2bu(hn);  // transpose tile (same-wave)
      }
      // repack: lane -> 8B chunk into slot t+1
      int b2 = lane >> 2, j0l = (lane & 3) * 4;
      unsigned long long pv = *(const unsigned long long*)&hrep[mt][b2][j0l];
      int bS = bbase + mt * 16 + b2, jS = jbase + j0l;
      __hip_atomic_store((unsigned long long*)(myh + (size_t)(t + 1) * BH + bS * 512 + jS), pv,
                         __ATOMIC_RELAXED, __HIP_MEMORY_SCOPE_AGENT);
      if (t == T - 1) {
#pragma unroll
        for (int r = 0; r < 4; r++) {
          int b = bE0 + r;
          out[OUT_HT + LAYER * BH + b * 512 + jE] = hnv[r];
          out[OUT_CT + LAYER * BH + b * 512 + jE] = cnv[r];
        }
      }
    }
    __syncthreads();  // drains epilogue stores; protects red WAR
    if (tid == 0) {
      __builtin_amdgcn_s_waitcnt(0);
      __hip_atomic_fetch_add(cmy + (t + 1), 1u, __ATOMIC_RELAXED, __HIP_MEMORY_SCOPE_AGENT);
    }
  }
}

__global__ __launch_bounds__(256, 1) void lstm_persist(
    const float* x, const int* done, const float* h0in, const float* c0in,
    const float* Wih0, const float* Whh0, const float* bih0, const float* bhh0,
    const float* Wih1, const float* Whh1, const float* bih1, const float* bhh1,
    float* out, unsigned short* h0h, unsigned short* h1h, unsigned int* cnt) {
  __shared__ float red[8192];
  __shared__ unsigned short hrep[2][16][20];
  const int bid = blockIdx.x;
  const int layer = bid >> 7;
  const int bl = bid & 127;
  const int bg = bl >> 5, jg = bl & 31;
  if (layer == 0)
    lstm_layer<0>(x, done, h0in, c0in, Wih0, Whh0, bih0, bhh0, out, h0h, h1h, cnt, bg, jg, red, hrep);
  else
    lstm_layer<1>(x, done, h0in, c0in, Wih1, Whh1, bih1, bhh1, out, h0h, h1h, cnt, bg, jg, red, hrep);
}

// heads: out[m, 0..18] = hidden[m,:] @ [W_actor; W_critic]^T + bias
__global__ __launch_bounds__(256) void head_kernel(const unsigned short* __restrict__ hidden,
                                                   const float* __restrict__ Wa, const float* __restrict__ ba,
                                                   const float* __restrict__ Wc, const float* __restrict__ bc,
                                                   float* __restrict__ out) {
  const int tid = threadIdx.x, w = tid >> 6, lane = tid & 63, lo = lane & 15, quad = lane >> 4;
  const int mbase = blockIdx.x * 128;
  s16x8 Bf[2][16];
#pragma unroll
  for (int nt = 0; nt < 2; nt++) {
    int row = nt * 16 + lo;
#pragma unroll
    for (int kc = 0; kc < 16; kc++) {
      int kg = kc * 32 + quad * 8;
      union { s16x8 v; unsigned short u[8]; } tu;
      if (row < 18) {
        const float* s = Wa + row * 512 + kg;
#pragma unroll
        for (int j = 0; j < 8; j++) tu.u[j] = f2bu(s[j]);
      } else if (row == 18) {
        const float* s = Wc + kg;
#pragma unroll
        for (int j = 0; j < 8; j++) tu.u[j] = f2bu(s[j]);
      } else {
        tu.v = s16x8{};
      }
      Bf[nt][kc] = tu.v;
    }
  }
  f32x4 acc[2][2];
#pragma unroll
  for (int mi = 0; mi < 2; mi++)
#pragma unroll
    for (int nt = 0; nt < 2; nt++) acc[mi][nt] = (f32x4){0.f, 0.f, 0.f, 0.f};
#pragma unroll
  for (int kc = 0; kc < 16; kc++) {
#pragma unroll
    for (int mi = 0; mi < 2; mi++) {
      int m = mbase + (w * 2 + mi) * 16 + lo;
      s16x8 a = *reinterpret_cast<const s16x8*>(hidden + (size_t)m * 512 + kc * 32 + quad * 8);
      acc[mi][0] = __builtin_amdgcn_mfma_f32_16x16x32_bf16(a, Bf[0][kc], acc[mi][0], 0, 0, 0);
      acc[mi][1] = __builtin_amdgcn_mfma_f32_16x16x32_bf16(a, Bf[1][kc], acc[mi][1], 0, 0, 0);
    }
  }
  float b0 = ba[lo];
  float b1 = (lo < 2) ? ba[16 + lo] : ((lo == 2) ? bc[0] : 0.f);
#pragma unroll
  for (int mi = 0; mi < 2; mi++)
#pragma unroll
    for (int r = 0; r < 4; r++) {
      int m = mbase + (w * 2 + mi) * 16 + quad * 4 + r;
      out[(size_t)m * 19 + lo] = acc[mi][0][r] + b0;
      if (lo < 3) out[(size_t)m * 19 + 16 + lo] = acc[mi][1][r] + b1;
    }
}

extern "C" void kernel_launch(void* const* d_in, const int* in_sizes, int n_in,
                              void* d_out, int out_size, void* d_ws, size_t ws_size,
                              hipStream_t stream) {
  const float* x = (const float*)d_in[0];
  const int* done = (const int*)d_in[1];
  const float* h0 = (const float*)d_in[2];
  const float* c0 = (const float*)d_in[3];
  const float* Wih0 = (const float*)d_in[4];
  const float* Whh0 = (const float*)d_in[5];
  const float* bih0 = (const float*)d_in[6];
  const float* bhh0 = (const float*)d_in[7];
  const float* Wih1 = (const float*)d_in[8];
  const float* Whh1 = (const float*)d_in[9];
  const float* bih1 = (const float*)d_in[10];
  const float* bhh1 = (const float*)d_in[11];
  const float* Wa = (const float*)d_in[12];
  const float* ba = (const float*)d_in[13];
  const float* Wc = (const float*)d_in[14];
  const float* bc = (const float*)d_in[15];
  float* out = (float*)d_out;

  char* ws = (char*)d_ws;
  const size_t cntBytes = 32768;                         // 2 layers x 4 bg x 1024 slots x 4B
  const size_t h0Off = cntBytes;
  const size_t h1Off = h0Off + (size_t)(T + 1) * BH * 2; // 67.24 MB each
  // total ~134.5 MB (ws_size >= 338 MB established in R3/R4)

  unsigned int* cnt = (unsigned int*)ws;
  unsigned short* h0h = (unsigned short*)(ws + h0Off);
  unsigned short* h1h = (unsigned short*)(ws + h1Off);

  hipMemsetAsync(cnt, 0, cntBytes, stream);
  lstm_persist<<<dim3(256), dim3(256), 0, stream>>>(
      x, done, h0, c0, Wih0, Whh0, bih0, bhh0, Wih1, Whh1, bih1, bhh1,
      out, h0h, h1h, cnt);
  head_kernel<<<dim3(512), dim3(256), 0, stream>>>(h1h + BH, Wa, ba, Wc, bc, out);
}

// Round 6
// 6492.358 us; speedup vs baseline: 1.1578x; 1.1578x over previous
//
#include <hip/hip_runtime.h>
#include <hip/hip_bf16.h>

// 2-layer LSTM (T=512,B=128,IN=544,H=512) + actor/critic heads on MI355X.
// R6: XCD-local dataflow. R2/R5 invariance (~13us/step across 3 sync
// mechanisms) => pole is per-step IF$ round trips (sc1 stores + contended
// same-line RMW polls + 8B IF$ data loads, per-XCD x re-fetch). Fix: place
// each (layer,bg) 32-block group on ONE XCD via the empirical bid%8 mapping,
// VERIFIED at runtime with s_getreg(HW_REG_XCC_ID); recurrent h goes through
// the group's own L2 with plain 16B ops (write-once addresses => no stale
// lines). Fallback (check fails) = R5's IF$-atomic path, always correct.
// Only L0->L1 crosses XCDs (dual-store: plain local + sc1 IF$ copy) and is
// pipeline lag, not rate. Counter slots padded to 64B; one poller lane per
// dependency + LDS-token release; x-waves never poll.
// Block decode: xg=bid&7 (XCD guess), jg=bid>>3; layer=xg>>2, bg=xg&3.
// ws: xcc/ck 4KB | counters 512KB | h0loc,h0ifc,h1loc,h1ifc 4x67.24MB = 269.5MB.

namespace {
constexpr int T = 512, B = 128, H = 512, NA = 18;
constexpr int BH = B * H;                 // 65536
constexpr int OUT_COLS = NA + 1;          // 19
constexpr int OUT_HT = T * B * OUT_COLS;  // 1245184
constexpr int OUT_CT = OUT_HT + 2 * BH;   // 1376256
constexpr int CSTRIDE = 16;               // uints per counter slot (64B line)
}

using f32x4 = __attribute__((ext_vector_type(4))) float;
using s16x8 = __attribute__((ext_vector_type(8))) short;

__device__ __forceinline__ unsigned short f2bu(float f) {
  union { __hip_bfloat16 h; unsigned short u; } cv;
  cv.h = __float2bfloat16(f);
  return cv.u;
}
__device__ __forceinline__ float sigm(float x) { return 1.0f / (1.0f + __expf(-x)); }
__device__ __forceinline__ float tanh_f(float x) { return 1.0f - 2.0f / (1.0f + __expf(2.0f * x)); }

__device__ __forceinline__ unsigned rmw_peek(unsigned* p) {
  return __hip_atomic_fetch_add(p, 0u, __ATOMIC_RELAXED, __HIP_MEMORY_SCOPE_AGENT);
}

__device__ __forceinline__ s16x8 ld_frag_agent(const unsigned short* p) {
  const unsigned long long* q = (const unsigned long long*)p;
  unsigned long long a0 = __hip_atomic_load(q, __ATOMIC_RELAXED, __HIP_MEMORY_SCOPE_AGENT);
  unsigned long long a1 = __hip_atomic_load(q + 1, __ATOMIC_RELAXED, __HIP_MEMORY_SCOPE_AGENT);
  union { unsigned long long u[2]; s16x8 v; } r;
  r.u[0] = a0; r.u[1] = a1;
  return r.v;
}

__device__ __forceinline__ s16x8 cvt8(const float* p) {
  const f32x4* q = (const f32x4*)p;
  f32x4 a = q[0], b = q[1];
  union { s16x8 v; unsigned short u[8]; } t;
#pragma unroll
  for (int j = 0; j < 4; j++) { t.u[j] = f2bu(a[j]); t.u[4 + j] = f2bu(b[j]); }
  return t.v;
}

// slot s holds h after step s-1 (slot 0 = initial h). Counter slot s counts
// publisher blocks (target 32). oloc: plain stores (XCD-local consumers);
// oifc: sc1/IF$ copy (cross-XCD consumers + fallback).
template <int LAYER>
__device__ void lstm_layer(const float* __restrict__ x, const int* __restrict__ done,
                           const float* __restrict__ h0in, const float* __restrict__ c0in,
                           const float* __restrict__ Wih, const float* __restrict__ Whh,
                           const float* __restrict__ bih, const float* __restrict__ bhh,
                           float* __restrict__ out,
                           unsigned short* __restrict__ oloc, unsigned short* __restrict__ oifc,
                           const unsigned short* __restrict__ iifc,
                           unsigned* cmy, unsigned* cin, int bg, int jg, float* red,
                           unsigned short (*hrep)[16][20], volatile unsigned* tok, bool fast) {
  constexpr int NKCMAX = (LAYER == 0) ? 9 : 8;
  const int tid = threadIdx.x;
  const int w = tid >> 6;
  const int lane = tid & 63;
  const int lo = lane & 15;
  const int quad = lane >> 4;
  const int bbase = bg * 32, jbase = jg * 16;
  const bool rec = (w >= 2);  // waves 2,3: recurrent operand

  int kbeg, nkc;
  if (LAYER == 0) { kbeg = (w == 0) ? 0 : (1 + w * 8); nkc = (w == 0) ? 9 : 8; }  // x: 0..16, h: 17..32
  else            { kbeg = w * 8; nkc = 8; }                                       // in: 0..15, h: 16..31

  // ---- weight B-fragments in registers ----
  s16x8 Bf[4][NKCMAX];
#pragma unroll
  for (int kci = 0; kci < NKCMAX; kci++) {
    if (kci < nkc) {
      int kg = (kbeg + kci) * 32 + quad * 8;
#pragma unroll
      for (int nt = 0; nt < 4; nt++) {
        int row = nt * 512 + jbase + lo;
        const float* src;
        if (LAYER == 0) src = (kg < 544) ? (Wih + (size_t)row * 544 + kg) : (Whh + (size_t)row * 512 + (kg - 544));
        else            src = (kg < 512) ? (Wih + (size_t)row * 512 + kg) : (Whh + (size_t)row * 512 + (kg - 512));
        Bf[nt][kci] = cvt8(src);
      }
    }
  }

  float bias[4];
#pragma unroll
  for (int nt = 0; nt < 4; nt++) {
    int row = nt * 512 + jbase + lo;
    bias[nt] = bih[row] + bhh[row];
  }

  const int mt = w & 1;
  const int bE0 = bbase + mt * 16 + quad * 4;
  const int jE = jbase + lo;
  float cst[4] = {0.f, 0.f, 0.f, 0.f};

  if (w < 2) {
#pragma unroll
    for (int r = 0; r < 4; r++) cst[r] = c0in[LAYER * BH + (bE0 + r) * 512 + jE];
    // initial h into slot 0: lane -> 8B chunk; dual store
    int bI = bbase + mt * 16 + (lane >> 2);
    int jI = jbase + (lane & 3) * 4;
    const float* hp = h0in + LAYER * BH + bI * 512 + jI;
    union { unsigned long long u; unsigned short s[4]; } pk;
#pragma unroll
    for (int j = 0; j < 4; j++) pk.s[j] = f2bu(hp[j]);
    size_t off0 = (size_t)bI * 512 + jI;
    *(unsigned long long*)(oloc + off0) = pk.u;
    __hip_atomic_store((unsigned long long*)(oifc + off0), pk.u,
                       __ATOMIC_RELAXED, __HIP_MEMORY_SCOPE_AGENT);
  }
  __syncthreads();
  if (tid == 0) {
    __builtin_amdgcn_s_waitcnt(0);
    __hip_atomic_fetch_add(cmy + 0, 1u, __ATOMIC_RELAXED, __HIP_MEMORY_SCOPE_AGENT);
  }

  for (int t = 0; t < T; t++) {
    // ---- dependency waits: one poller lane per dep, LDS-token release ----
    if (rec) {
      if (w == 2 && lane == 0) {
        while (rmw_peek(cmy + t * CSTRIDE) < 32u) __builtin_amdgcn_s_sleep(2);
        tok[0] = (unsigned)(t + 1);
      }
      while (tok[0] < (unsigned)(t + 1)) __builtin_amdgcn_s_sleep(1);
    } else if (LAYER == 1) {
      if (w == 0 && lane == 0) {
        while (rmw_peek(cin + (t + 1) * CSTRIDE) < 32u) __builtin_amdgcn_s_sleep(2);
        tok[1] = (unsigned)(t + 1);
      }
      while (tok[1] < (unsigned)(t + 1)) __builtin_amdgcn_s_sleep(1);
    }
    // L0 waves 0,1 (x-part): no wait at all.

    const unsigned short* precL[2];
    const unsigned short* precI[2];
    const unsigned short* pin1[2];
    const float* pxf[2];
    bool dA[2];
#pragma unroll
    for (int m2 = 0; m2 < 2; m2++) {
      int b = bbase + m2 * 16 + lo;
      dA[m2] = rec ? (done[t * B + b] != 0) : false;
      size_t roff = (size_t)t * BH + b * 512 + quad * 8;
      precL[m2] = oloc + roff;
      precI[m2] = oifc + roff;
      if (LAYER == 0) pxf[m2] = x + (size_t)(t * B + b) * 544 + quad * 8;
      else            pin1[m2] = iifc + (size_t)(t + 1) * BH + b * 512 + quad * 8;
    }
    const int koff = rec ? (kbeg - (LAYER == 0 ? 17 : 16)) * 32 : kbeg * 32;

    f32x4 acc[2][4];
#pragma unroll
    for (int m2 = 0; m2 < 2; m2++)
#pragma unroll
      for (int nt = 0; nt < 4; nt++) acc[m2][nt] = (f32x4){0.f, 0.f, 0.f, 0.f};

#pragma unroll
    for (int kci = 0; kci < NKCMAX; kci++) {
      if (kci < nkc) {
        int ko = koff + kci * 32;
#pragma unroll
        for (int m2 = 0; m2 < 2; m2++) {
          s16x8 a;
          if (rec) {
            a = fast ? *reinterpret_cast<const s16x8*>(precL[m2] + ko)   // L2-local 16B
                     : ld_frag_agent(precI[m2] + ko);                    // IF$ fallback
            if (dA[m2]) a = s16x8{};
          } else if (LAYER == 0) {
            a = cvt8(pxf[m2] + ko);
          } else {
            a = ld_frag_agent(pin1[m2] + ko);                            // cross-XCD input
          }
#pragma unroll
          for (int nt = 0; nt < 4; nt++)
            acc[m2][nt] = __builtin_amdgcn_mfma_f32_16x16x32_bf16(a, Bf[nt][kci], acc[m2][nt], 0, 0, 0);
        }
      }
    }

    // cross-wave K reduction through LDS
#pragma unroll
    for (int m2 = 0; m2 < 2; m2++)
#pragma unroll
      for (int nt = 0; nt < 4; nt++)
#pragma unroll
        for (int r = 0; r < 4; r++)
          red[(((w * 2 + m2) * 16) + nt * 4 + r) * 64 + lane] = acc[m2][nt][r];
    __syncthreads();  // barrier A

    if (w < 2) {
      float g[4][4];
#pragma unroll
      for (int nt = 0; nt < 4; nt++)
#pragma unroll
        for (int r = 0; r < 4; r++) {
          int f = nt * 4 + r;
          g[nt][r] = red[((0 * 2 + mt) * 16 + f) * 64 + lane] + red[((1 * 2 + mt) * 16 + f) * 64 + lane] +
                     red[((2 * 2 + mt) * 16 + f) * 64 + lane] + red[((3 * 2 + mt) * 16 + f) * 64 + lane];
        }
      float hnv[4], cnv[4];
#pragma unroll
      for (int r = 0; r < 4; r++) {
        int b = bE0 + r;
        float iv = g[0][r] + bias[0];
        float fv = g[1][r] + bias[1];
        float gv = g[2][r] + bias[2];
        float ov = g[3][r] + bias[3];
        float cp = (done[t * B + b] != 0) ? 0.0f : cst[r];
        float cn = sigm(fv) * cp + sigm(iv) * tanh_f(gv);
        float hn = sigm(ov) * tanh_f(cn);
        cst[r] = cn; hnv[r] = hn; cnv[r] = cn;
        hrep[mt][quad * 4 + r][lo] = f2bu(hn);  // transpose tile (same-wave)
      }
      // repack: lane -> 8B chunk into slot t+1; dual store
      int b2 = lane >> 2, j0l = (lane & 3) * 4;
      unsigned long long pv = *(const unsigned long long*)&hrep[mt][b2][j0l];
      int bS = bbase + mt * 16 + b2, jS = jbase + j0l;
      size_t soff = (size_t)(t + 1) * BH + bS * 512 + jS;
      *(unsigned long long*)(oloc + soff) = pv;
      __hip_atomic_store((unsigned long long*)(oifc + soff), pv,
                         __ATOMIC_RELAXED, __HIP_MEMORY_SCOPE_AGENT);
      if (t == T - 1) {
#pragma unroll
        for (int r = 0; r < 4; r++) {
          int b = bE0 + r;
          out[OUT_HT + LAYER * BH + b * 512 + jE] = hnv[r];
          out[OUT_CT + LAYER * BH + b * 512 + jE] = cnv[r];
        }
      }
    }
    __syncthreads();  // barrier B: drains all waves' stores; protects red WAR
    if (tid == 0) {
      __builtin_amdgcn_s_waitcnt(0);
      __hip_atomic_fetch_add(cmy + (t + 1) * CSTRIDE, 1u, __ATOMIC_RELAXED, __HIP_MEMORY_SCOPE_AGENT);
    }
  }
}

__global__ __launch_bounds__(256, 1) void lstm_persist(
    const float* x, const int* done, const float* h0in, const float* c0in,
    const float* Wih0, const float* Whh0, const float* bih0, const float* bhh0,
    const float* Wih1, const float* Whh1, const float* bih1, const float* bhh1,
    float* out, unsigned short* h0loc, unsigned short* h0ifc,
    unsigned short* h1loc, unsigned short* h1ifc,
    unsigned* cnt, unsigned* xcc) {
  __shared__ float red[8192];
  __shared__ unsigned short hrep[2][16][20];
  __shared__ unsigned tok[2];
  __shared__ int sameSh;
  const int tid = threadIdx.x;
  const int bid = blockIdx.x;
  const int xg = bid & 7, jg = bid >> 3;
  const int layer = xg >> 2, bg = xg & 3;
  const int w = tid >> 6, lane = tid & 63;

  if (tid < 2) tok[tid] = 0;

  // ---- one-time XCD co-location check (agent-scope, always correct) ----
  unsigned* ckall = xcc + 256;
  if (tid == 0) {
    unsigned myxcc = 0;
    asm volatile("s_getreg_b32 %0, hwreg(20, 0, 32)" : "=s"(myxcc));
    __hip_atomic_store(xcc + bid, myxcc, __ATOMIC_RELAXED, __HIP_MEMORY_SCOPE_AGENT);
    __builtin_amdgcn_s_waitcnt(0);
    __hip_atomic_fetch_add(ckall, 1u, __ATOMIC_RELAXED, __HIP_MEMORY_SCOPE_AGENT);
    while (rmw_peek(ckall) < 256u) __builtin_amdgcn_s_sleep(8);
  }
  __syncthreads();
  if (w == 0) {
    unsigned ref = __hip_atomic_load(xcc + bid, __ATOMIC_RELAXED, __HIP_MEMORY_SCOPE_AGENT);
    unsigned pid = ref;
    if (lane < 32) pid = __hip_atomic_load(xcc + (lane * 8 + xg), __ATOMIC_RELAXED, __HIP_MEMORY_SCOPE_AGENT);
    int ok = __all((int)(pid == ref));
    if (lane == 0) sameSh = ok;
  }
  __syncthreads();
  const bool fast = (sameSh != 0);

  unsigned* c0arr = cnt + (size_t)(0 + bg) * 513 * CSTRIDE;
  unsigned* c1arr = cnt + (size_t)(4 + bg) * 513 * CSTRIDE;

  if (layer == 0)
    lstm_layer<0>(x, done, h0in, c0in, Wih0, Whh0, bih0, bhh0, out,
                  h0loc, h0ifc, nullptr, c0arr, nullptr, bg, jg, red, hrep, tok, fast);
  else
    lstm_layer<1>(x, done, h0in, c0in, Wih1, Whh1, bih1, bhh1, out,
                  h1loc, h1ifc, h0ifc, c1arr, c0arr, bg, jg, red, hrep, tok, fast);
}

// heads: out[m, 0..18] = hidden[m,:] @ [W_actor; W_critic]^T + bias
__global__ __launch_bounds__(256) void head_kernel(const unsigned short* __restrict__ hidden,
                                                   const float* __restrict__ Wa, const float* __restrict__ ba,
                                                   const float* __restrict__ Wc, const float* __restrict__ bc,
                                                   float* __restrict__ out) {
  const int tid = threadIdx.x, w = tid >> 6, lane = tid & 63, lo = lane & 15, quad = lane >> 4;
  const int mbase = blockIdx.x * 128;
  s16x8 Bf[2][16];
#pragma unroll
  for (int nt = 0; nt < 2; nt++) {
    int row = nt * 16 + lo;
#pragma unroll
    for (int kc = 0; kc < 16; kc++) {
      int kg = kc * 32 + quad * 8;
      union { s16x8 v; unsigned short u[8]; } tu;
      if (row < 18) {
        const float* s = Wa + row * 512 + kg;
#pragma unroll
        for (int j = 0; j < 8; j++) tu.u[j] = f2bu(s[j]);
      } else if (row == 18) {
        const float* s = Wc + kg;
#pragma unroll
        for (int j = 0; j < 8; j++) tu.u[j] = f2bu(s[j]);
      } else {
        tu.v = s16x8{};
      }
      Bf[nt][kc] = tu.v;
    }
  }
  f32x4 acc[2][2];
#pragma unroll
  for (int mi = 0; mi < 2; mi++)
#pragma unroll
    for (int nt = 0; nt < 2; nt++) acc[mi][nt] = (f32x4){0.f, 0.f, 0.f, 0.f};
#pragma unroll
  for (int kc = 0; kc < 16; kc++) {
#pragma unroll
    for (int mi = 0; mi < 2; mi++) {
      int m = mbase + (w * 2 + mi) * 16 + lo;
      s16x8 a = *reinterpret_cast<const s16x8*>(hidden + (size_t)m * 512 + kc * 32 + quad * 8);
      acc[mi][0] = __builtin_amdgcn_mfma_f32_16x16x32_bf16(a, Bf[0][kc], acc[mi][0], 0, 0, 0);
      acc[mi][1] = __builtin_amdgcn_mfma_f32_16x16x32_bf16(a, Bf[1][kc], acc[mi][1], 0, 0, 0);
    }
  }
  float b0 = ba[lo];
  float b1 = (lo < 2) ? ba[16 + lo] : ((lo == 2) ? bc[0] : 0.f);
#pragma unroll
  for (int mi = 0; mi < 2; mi++)
#pragma unroll
    for (int r = 0; r < 4; r++) {
      int m = mbase + (w * 2 + mi) * 16 + quad * 4 + r;
      out[(size_t)m * 19 + lo] = acc[mi][0][r] + b0;
      if (lo < 3) out[(size_t)m * 19 + 16 + lo] = acc[mi][1][r] + b1;
    }
}

extern "C" void kernel_launch(void* const* d_in, const int* in_sizes, int n_in,
                              void* d_out, int out_size, void* d_ws, size_t ws_size,
                              hipStream_t stream) {
  const float* x = (const float*)d_in[0];
  const int* done = (const int*)d_in[1];
  const float* h0 = (const float*)d_in[2];
  const float* c0 = (const float*)d_in[3];
  const float* Wih0 = (const float*)d_in[4];
  const float* Whh0 = (const float*)d_in[5];
  const float* bih0 = (const float*)d_in[6];
  const float* bhh0 = (const float*)d_in[7];
  const float* Wih1 = (const float*)d_in[8];
  const float* Whh1 = (const float*)d_in[9];
  const float* bih1 = (const float*)d_in[10];
  const float* bhh1 = (const float*)d_in[11];
  const float* Wa = (const float*)d_in[12];
  const float* ba = (const float*)d_in[13];
  const float* Wc = (const float*)d_in[14];
  const float* bc = (const float*)d_in[15];
  float* out = (float*)d_out;

  char* ws = (char*)d_ws;
  const size_t cntOff = 4096;                         // xcc[256]+ckall in [0,4096)
  const size_t cntBytes = 524288;                     // 8 grp x 513 slot x 64B = 262656, padded
  const size_t HSLOT = (size_t)(T + 1) * BH * 2;      // 67,239,936 B
  const size_t h0locOff = cntOff + cntBytes;          // 528,384
  const size_t h0ifcOff = h0locOff + HSLOT;
  const size_t h1locOff = h0ifcOff + HSLOT;
  const size_t h1ifcOff = h1locOff + HSLOT;           // end ~269.5 MB (< established ws)

  unsigned* xcc = (unsigned*)ws;
  unsigned* cnt = (unsigned*)(ws + cntOff);
  unsigned short* h0loc = (unsigned short*)(ws + h0locOff);
  unsigned short* h0ifc = (unsigned short*)(ws + h0ifcOff);
  unsigned short* h1loc = (unsigned short*)(ws + h1locOff);
  unsigned short* h1ifc = (unsigned short*)(ws + h1ifcOff);

  hipMemsetAsync(ws, 0, cntOff + cntBytes, stream);
  lstm_persist<<<dim3(256), dim3(256), 0, stream>>>(
      x, done, h0, c0, Wih0, Whh0, bih0, bhh0, Wih1, Whh1, bih1, bhh1,
      out, h0loc, h0ifc, h1loc, h1ifc, cnt, xcc);
  head_kernel<<<dim3(512), dim3(256), 0, stream>>>(h1loc + BH, Wa, ba, Wc, bc, out);
}